// Round 9
// baseline (2976.522 us; speedup 1.0000x reference)
//
#include <hip/hip_runtime.h>
#include <math.h>

#define NTOK 4096
#define HDIM 1024
#define NHEADS 16
#define HD 64
#define SEQ 2048
#define WSZ (HDIM*HDIM)
#define NM (NTOK*HDIM)
#define SQ7F 2.6457513110645906f   // float32(math.sqrt(7.0))
#define KC_BLK 384                 // OpenBLAS sgemm KC (k-panel) size

// Workspace (floats): wm4[0..3] | M (4*WSZ) | XD (NM, later ctx) | Q (NM, later cqm) | K | V

__device__ __forceinline__ float lane_bcast_f(float v, int l) {
  return __builtin_bit_cast(float, __builtin_amdgcn_readlane(__builtin_bit_cast(int, v), l));
}

// numpy pairwise_sum base case, n=128: 8 accumulators, ((r0+r1)+(r2+r3))+((r4+r5)+(r6+r7))
__device__ __forceinline__ float np_block128_abs(const float* a) {
  float r[8];
#pragma unroll
  for (int j = 0; j < 8; j++) r[j] = fabsf(a[j]);
  for (int i = 8; i < 128; i += 8)
#pragma unroll
    for (int j = 0; j < 8; j++) r[j] = __fadd_rn(r[j], fabsf(a[i + j]));
  return __fadd_rn(__fadd_rn(__fadd_rn(r[0], r[1]), __fadd_rn(r[2], r[3])),
                   __fadd_rn(__fadd_rn(r[4], r[5]), __fadd_rn(r[6], r[7])));
}
__device__ __forceinline__ float np_block128(const float* a) {
  float r[8];
#pragma unroll
  for (int j = 0; j < 8; j++) r[j] = a[j];
  for (int i = 8; i < 128; i += 8)
#pragma unroll
    for (int j = 0; j < 8; j++) r[j] = __fadd_rn(r[j], a[i + j]);
  return __fadd_rn(__fadd_rn(__fadd_rn(r[0], r[1]), __fadd_rn(r[2], r[3])),
                   __fadd_rn(__fadd_rn(r[4], r[5]), __fadd_rn(r[6], r[7])));
}

// ---- w_mean = np.mean(|W|) over 1M, exact numpy pairwise tree ----
__global__ __launch_bounds__(1024) void k_wmean_np(const float* __restrict__ Wq,
                                                   const float* __restrict__ Wk,
                                                   const float* __restrict__ Wv,
                                                   const float* __restrict__ Wo,
                                                   float* __restrict__ wm4) {
  __shared__ float bsA[8192];
  __shared__ float bsB[4096];
  int w = blockIdx.x, t = threadIdx.x;
  const float* W = (w == 0) ? Wq : (w == 1) ? Wk : (w == 2) ? Wv : Wo;
  for (int r = 0; r < 8; r++) {
    int blk = t * 8 + r;
    bsA[blk] = np_block128_abs(W + blk * 128);
  }
  __syncthreads();
  float* cur = bsA;
  float* nxt = bsB;
  for (int len = 4096; len >= 1; len >>= 1) {
    for (int i = t; i < len; i += 1024)
      nxt[i] = __fadd_rn(cur[2 * i], cur[2 * i + 1]);
    __syncthreads();
    float* tmp = cur; cur = nxt; nxt = tmp;
  }
  if (t == 0) wm4[w] = cur[0] / 1048576.0f;   // exact /2^20
}

// ---- M = fl(fl(round-clip(W/(wm+1e-5)) * wm) * s) ----
__global__ void k_wquant_np(const float* __restrict__ Wq, const float* __restrict__ Wk,
                            const float* __restrict__ Wv, const float* __restrict__ Wo,
                            const float* __restrict__ wm4, float* __restrict__ M,
                            const float* __restrict__ sq, const float* __restrict__ sk,
                            const float* __restrict__ sv, const float* __restrict__ so) {
  int w = blockIdx.y;
  const float* W = (w == 0) ? Wq : (w == 1) ? Wk : (w == 2) ? Wv : Wo;
  float s = (w == 0) ? sq[0] : (w == 1) ? sk[0] : (w == 2) ? sv[0] : so[0];
  float wm = wm4[w];
  float wme = __fadd_rn(wm, 1e-5f);
  int i = blockIdx.x * 1024 + threadIdx.x * 4;
  float4 v = *(const float4*)(W + i);
  float4 o;
  o.x = __fmul_rn(__fmul_rn(fminf(fmaxf(rintf(__fdiv_rn(v.x, wme)), -1.f), 1.f), wm), s);
  o.y = __fmul_rn(__fmul_rn(fminf(fmaxf(rintf(__fdiv_rn(v.y, wme)), -1.f), 1.f), wm), s);
  o.z = __fmul_rn(__fmul_rn(fminf(fmaxf(rintf(__fdiv_rn(v.z, wme)), -1.f), 1.f), wm), s);
  o.w = __fmul_rn(__fmul_rn(fminf(fmaxf(rintf(__fdiv_rn(v.w, wme)), -1.f), 1.f), wm), s);
  *(float4*)(M + (size_t)w * WSZ + i) = o;
}

// ---- int4 quant: beta = np.mean(|row|) pairwise; xd = dequant, f32 np op order ----
__global__ __launch_bounds__(64) void k_xquant_np(const float* __restrict__ x,
                                                  float* __restrict__ xd) {
  int n = blockIdx.x * 64 + threadIdx.x;
  const float* row = x + (size_t)n * HDIM;
  float bs[8];
#pragma unroll
  for (int b = 0; b < 8; b++) bs[b] = np_block128_abs(row + b * 128);
  float total = __fadd_rn(__fadd_rn(__fadd_rn(bs[0], bs[1]), __fadd_rn(bs[2], bs[3])),
                          __fadd_rn(__fadd_rn(bs[4], bs[5]), __fadd_rn(bs[6], bs[7])));
  float beta = total / 1024.0f;
  float bpe = __fadd_rn(beta, 1e-5f);
  float scale = __fmul_rn(beta, SQ7F);
  float* od = xd + (size_t)n * HDIM;
  for (int i = 0; i < 1024; i++) {
    float q = fminf(fmaxf(rintf(__fdiv_rn(__fmul_rn(row[i], SQ7F), bpe)), -8.f), 7.f);
    od[i] = __fdiv_rn(__fmul_rn(q, scale), SQ7F);
  }
}

// ---- GEMM replicating BLAS sgemm accumulation (KC=384 sequential fma chains) ----
__global__ __launch_bounds__(256) void k_gemm_blas(const float* __restrict__ A,
                                                   const float* __restrict__ Bm,
                                                   float* __restrict__ C) {
  __shared__ __align__(16) float As[16 * 68];
  __shared__ __align__(16) float Bs[16 * 68];
  int t = threadIdx.x;
  int o0 = blockIdx.x * 64, n0 = blockIdx.y * 64;
  int lr = t >> 2, lc = (t & 3) * 4;
  const float* Ag = A + (size_t)(n0 + lr) * HDIM + lc;
  const float* Bg = Bm + (size_t)(o0 + lr) * HDIM + lc;
  int tn = (t & 15) * 4, to = (t >> 4) * 4;
  float acc[4][4] = {};    // current KC-block accumulator (sequential fma chain)
  float accP[4][4] = {};   // sum of completed blocks (left-assoc adds)
  for (int kt = 0; kt < HDIM; kt += 16) {
    if (kt == KC_BLK || kt == 2 * KC_BLK) {
#pragma unroll
      for (int i = 0; i < 4; i++)
#pragma unroll
        for (int j = 0; j < 4; j++) {
          accP[i][j] = __fadd_rn(accP[i][j], acc[i][j]);
          acc[i][j] = 0.f;
        }
    }
    float4 a = *(const float4*)(Ag + kt);
    float4 b = *(const float4*)(Bg + kt);
    __syncthreads();
    float av[4] = {a.x, a.y, a.z, a.w};
    float bv[4] = {b.x, b.y, b.z, b.w};
#pragma unroll
    for (int u = 0; u < 4; u++) {
      As[(lc + u) * 68 + lr] = av[u];
      Bs[(lc + u) * 68 + lr] = bv[u];
    }
    __syncthreads();
#pragma unroll
    for (int kc = 0; kc < 16; kc++) {
      float4 a4 = *(const float4*)&As[kc * 68 + tn];
      float4 b4 = *(const float4*)&Bs[kc * 68 + to];
      float aa[4] = {a4.x, a4.y, a4.z, a4.w};
      float bb[4] = {b4.x, b4.y, b4.z, b4.w};
#pragma unroll
      for (int i = 0; i < 4; i++)
#pragma unroll
        for (int j = 0; j < 4; j++)
          acc[i][j] = __fmaf_rn(aa[i], bb[j], acc[i][j]);
    }
  }
#pragma unroll
  for (int i = 0; i < 4; i++) {
    float4 v;
    v.x = __fadd_rn(accP[i][0], acc[i][0]);
    v.y = __fadd_rn(accP[i][1], acc[i][1]);
    v.z = __fadd_rn(accP[i][2], acc[i][2]);
    v.w = __fadd_rn(accP[i][3], acc[i][3]);
    *(float4*)(C + (size_t)(n0 + tn + i) * HDIM + o0 + to) = v;
  }
}

// ---- attention v3: bit-identical FP chains; [j][d] pad-68 KV tile (b128 paths),
//      132-stride padded erow (16B-aligned blocks, conflict-free np sums) ----
__global__ __launch_bounds__(256) void k_attn_np(const float* __restrict__ qb,
                                                 const float* __restrict__ kb,
                                                 const float* __restrict__ vb,
                                                 float* __restrict__ ctx) {
  __shared__ __align__(16) float KV[64 * 68];     // [j][d], byte stride 272 (16B-aligned)
  __shared__ __align__(16) float ebuf[4 * 2112];  // padded idx = idx + 4*(idx>>7)
  __shared__ __align__(16) float qs[4][64];
  int bh = blockIdx.y;
  int b = bh >> 4, h = bh & 15;
  int t = threadIdx.x, wave = t >> 6, lane = t & 63;
  int row = blockIdx.x * 4 + wave;
  size_t base = (size_t)b * SEQ * HDIM + h * HD;
  qs[wave][lane] = qb[base + (size_t)row * HDIM + lane];   // own-wave write/read, no barrier
  float* erow = ebuf + wave * 2112;
  int sj = t >> 2, part = t & 3;   // staging: key row sj, 16-float quarter `part`

  // ---- Phase 1: scores (einsum SSE 4-acc chain; d = 4g+{x,y,z,w} identical to R8) ----
  for (int c = 0; c < 32; c++) {
    __syncthreads();
    const float* kg = kb + base + (size_t)(c * 64 + sj) * HDIM + part * 16;
    float* dst = &KV[sj * 68 + part * 16];
#pragma unroll
    for (int u = 0; u < 4; u++)
      *(float4*)(dst + u * 4) = *(const float4*)(kg + u * 4);
    __syncthreads();
    float c4[4] = {0.f, 0.f, 0.f, 0.f};
    const float* krow = &KV[lane * 68];
    const float* qp = &qs[wave][0];
#pragma unroll
    for (int g = 0; g < 16; g++) {
      float4 k4 = *(const float4*)(krow + g * 4);
      float4 q4 = *(const float4*)(qp + g * 4);    // uniform broadcast
      c4[0] = __fadd_rn(c4[0], __fmul_rn(q4.x, k4.x));
      c4[1] = __fadd_rn(c4[1], __fmul_rn(q4.y, k4.y));
      c4[2] = __fadd_rn(c4[2], __fmul_rn(q4.z, k4.z));
      c4[3] = __fadd_rn(c4[3], __fmul_rn(q4.w, k4.w));
    }
    float sr = __fadd_rn(__fadd_rn(c4[0], c4[2]), __fadd_rn(c4[1], c4[3]));
    erow[c * 64 + 4 * (c >> 1) + lane] = __fmul_rn(sr, 0.125f);   // padded store
  }

  // ---- softmax (ops identical to R8; padded idx = lane+64i+4*(i>>1)) ----
  float m = -INFINITY;
  for (int i = 0; i < 32; i++) m = fmaxf(m, erow[lane + 64 * i + 4 * (i >> 1)]);
#pragma unroll
  for (int off = 32; off; off >>= 1) m = fmaxf(m, __shfl_xor(m, off));
  for (int i = 0; i < 32; i++) {
    int idx = lane + 64 * i + 4 * (i >> 1);
    erow[idx] = (float)exp((double)__fadd_rn(erow[idx], -m));
  }
  int L = lane & 15;
  float bsum = np_block128(erow + 132 * L);   // contiguous 128-block, aligned, 2-way banks
  float b16[16];
#pragma unroll
  for (int j = 0; j < 16; j++) b16[j] = lane_bcast_f(bsum, j);
  float la = __fadd_rn(__fadd_rn(b16[0], b16[1]), __fadd_rn(b16[2], b16[3]));
  float lb = __fadd_rn(__fadd_rn(b16[4], b16[5]), __fadd_rn(b16[6], b16[7]));
  float lc2 = __fadd_rn(__fadd_rn(b16[8], b16[9]), __fadd_rn(b16[10], b16[11]));
  float ld = __fadd_rn(__fadd_rn(b16[12], b16[13]), __fadd_rn(b16[14], b16[15]));
  float S = __fadd_rn(__fadd_rn(la, lb), __fadd_rn(lc2, ld));
  for (int i = 0; i < 32; i++) {
    int idx = lane + 64 * i + 4 * (i >> 1);
    erow[idx] = __fdiv_rn(erow[idx], S);
  }

  // ---- Phase 2: PV, strictly sequential j (= 4u + {x,y,z,w}) per lane d ----
  float o = 0.f;
  for (int c = 0; c < 32; c++) {
    __syncthreads();
    const float* vg = vb + base + (size_t)(c * 64 + sj) * HDIM + part * 16;
    float* dst = &KV[sj * 68 + part * 16];
#pragma unroll
    for (int u = 0; u < 4; u++)
      *(float4*)(dst + u * 4) = *(const float4*)(vg + u * 4);
    __syncthreads();
    const float* erc = erow + c * 64 + 4 * (c >> 1);   // 16B-aligned uniform base
#pragma unroll
    for (int u = 0; u < 16; u++) {
      float4 p4 = *(const float4*)(erc + u * 4);       // uniform broadcast
      float v0 = KV[(4 * u + 0) * 68 + lane];
      float v1 = KV[(4 * u + 1) * 68 + lane];
      float v2 = KV[(4 * u + 2) * 68 + lane];
      float v3 = KV[(4 * u + 3) * 68 + lane];
      o = __fadd_rn(o, __fmul_rn(p4.x, v0));
      o = __fadd_rn(o, __fmul_rn(p4.y, v1));
      o = __fadd_rn(o, __fmul_rn(p4.z, v2));
      o = __fadd_rn(o, __fmul_rn(p4.w, v3));
    }
  }
  ctx[base + (size_t)row * HDIM + lane] = o;
}

// ---- int8 quant + topk: f32 np-order decisions, integer-level histogram ----
__global__ __launch_bounds__(256) void k_ctxq_np(const float* __restrict__ ctx,
                                                 float* __restrict__ cqm) {
  int n = blockIdx.x, t = threadIdx.x;
  __shared__ float red[256];
  __shared__ int hist[129];
  __shared__ int tsh;
  float4 cv = *(const float4*)(ctx + (size_t)n * HDIM + t * 4);
  float mx = fmaxf(fmaxf(fabsf(cv.x), fabsf(cv.y)), fmaxf(fabsf(cv.z), fabsf(cv.w)));
  red[t] = mx; __syncthreads();
  for (int st = 128; st > 0; st >>= 1) {
    if (t < st) red[t] = fmaxf(red[t], red[t + st]);
    __syncthreads();
  }
  float gamma = red[0];
  if (t < 129) hist[t] = 0;
  __syncthreads();
  float gpe = __fadd_rn(gamma, 1e-5f);
  float q0 = fminf(fmaxf(rintf(__fdiv_rn(__fmul_rn(cv.x, 127.0f), gpe)), -128.f), 127.f);
  float q1 = fminf(fmaxf(rintf(__fdiv_rn(__fmul_rn(cv.y, 127.0f), gpe)), -128.f), 127.f);
  float q2 = fminf(fmaxf(rintf(__fdiv_rn(__fmul_rn(cv.z, 127.0f), gpe)), -128.f), 127.f);
  float q3 = fminf(fmaxf(rintf(__fdiv_rn(__fmul_rn(cv.w, 127.0f), gpe)), -128.f), 127.f);
  int a0 = (int)fabsf(q0), a1 = (int)fabsf(q1), a2 = (int)fabsf(q2), a3 = (int)fabsf(q3);
  atomicAdd(&hist[a0], 1); atomicAdd(&hist[a1], 1);
  atomicAdd(&hist[a2], 1); atomicAdd(&hist[a3], 1);
  __syncthreads();
  if (t < 129) {
    int cum = 0;
    for (int u = 0; u <= t; u++) cum += hist[u];
    if (cum >= 512 && cum - hist[t] < 512) tsh = t;
  }
  __syncthreads();
  int thr = tsh;
  float4 o;
  o.x = (a0 >= thr) ? __fdiv_rn(__fmul_rn(q0, gamma), 127.0f) : 0.f;
  o.y = (a1 >= thr) ? __fdiv_rn(__fmul_rn(q1, gamma), 127.0f) : 0.f;
  o.z = (a2 >= thr) ? __fdiv_rn(__fmul_rn(q2, gamma), 127.0f) : 0.f;
  o.w = (a3 >= thr) ? __fdiv_rn(__fmul_rn(q3, gamma), 127.0f) : 0.f;
  *(float4*)(cqm + (size_t)n * HDIM + t * 4) = o;
}

extern "C" void kernel_launch(void* const* d_in, const int* in_sizes, int n_in,
                              void* d_out, int out_size, void* d_ws, size_t ws_size,
                              hipStream_t stream) {
  const float* x  = (const float*)d_in[0];
  const float* Wq = (const float*)d_in[1];
  const float* Wk = (const float*)d_in[2];
  const float* Wv = (const float*)d_in[3];
  const float* Wo = (const float*)d_in[4];
  const float* sq = (const float*)d_in[5];
  const float* sk = (const float*)d_in[6];
  const float* sv = (const float*)d_in[7];
  const float* so = (const float*)d_in[8];
  float* out = (float*)d_out;

  float* F   = (float*)d_ws;
  float* wm4 = F;
  float* M   = F + 1024;
  float* XD  = M + (size_t)4 * WSZ;
  float* Q   = XD + (size_t)NM;
  float* K   = Q + (size_t)NM;
  float* V   = K + (size_t)NM;
  float* ctx = XD;
  float* cqm = Q;

  k_wmean_np<<<4, 1024, 0, stream>>>(Wq, Wk, Wv, Wo, wm4);
  k_wquant_np<<<dim3(1024, 4), 256, 0, stream>>>(Wq, Wk, Wv, Wo, wm4, M, sq, sk, sv, so);
  k_xquant_np<<<64, 64, 0, stream>>>(x, XD);

  k_gemm_blas<<<dim3(16, 64), 256, 0, stream>>>(XD, M + 0 * (size_t)WSZ, Q);
  k_gemm_blas<<<dim3(16, 64), 256, 0, stream>>>(XD, M + 1 * (size_t)WSZ, K);
  k_gemm_blas<<<dim3(16, 64), 256, 0, stream>>>(XD, M + 2 * (size_t)WSZ, V);

  k_attn_np<<<dim3(512, 32), 256, 0, stream>>>(Q, K, V, ctx);

  k_ctxq_np<<<4096, 256, 0, stream>>>(ctx, cqm);

  k_gemm_blas<<<dim3(16, 64), 256, 0, stream>>>(cqm, M + 3 * (size_t)WSZ, out);
}